// Round 13
// baseline (194.038 us; speedup 1.0000x reference)
//
#include <hip/hip_runtime.h>

// B=4 T=2048 C=1024 H=16 D=64  N=B*T=8192

typedef __attribute__((ext_vector_type(8))) short short8;
typedef __attribute__((ext_vector_type(4))) short short4v;
typedef __attribute__((ext_vector_type(4))) float f32x4;

__device__ __forceinline__ unsigned short f2b(float f) {
  union { float f; unsigned int i; } x; x.f = f;
  return (unsigned short)((x.i + 0x7FFFu + ((x.i >> 16) & 1u)) >> 16);
}

// hardware RNE f32->bf16
__device__ __forceinline__ unsigned short b16(float f) {
  return __builtin_bit_cast(unsigned short, (__bf16)f);
}

__device__ __forceinline__ void glds16(const void* g, void* l) {
  __builtin_amdgcn_global_load_lds((const __attribute__((address_space(1))) unsigned int*)g,
                                   (__attribute__((address_space(3))) unsigned int*)l,
                                   16, 0, 0);
}

__device__ __forceinline__ f32x4 mfma16(short8 a, short8 b, f32x4 c) {
  return __builtin_amdgcn_mfma_f32_16x16x32_bf16(a, b, c, 0, 0, 0);
}

// ---------------- cast x: f32 -> bf16, 8 elems/thread ----------------
__global__ __launch_bounds__(256) void cast_x_kernel(const float* __restrict__ x,
                                                     unsigned short* __restrict__ xb) {
  const long i = ((long)blockIdx.x * 256 + threadIdx.x) * 8;
  const float4 a = *(const float4*)(x + i);
  const float4 b = *(const float4*)(x + i + 4);
  unsigned short o[8] = {f2b(a.x), f2b(a.y), f2b(a.z), f2b(a.w),
                         f2b(b.x), f2b(b.y), f2b(b.z), f2b(b.w)};
  *(short8*)(xb + i) = *(const short8*)o;
}

// ---------------- transpose+cast weights: dst[n][k] = W[k][n] ----------------
__global__ __launch_bounds__(256) void transpose_cast_w(
    const float* __restrict__ W0, const float* __restrict__ W1,
    const float* __restrict__ W2, const float* __restrict__ W3,
    unsigned short* __restrict__ Wt, unsigned short* __restrict__ Wot) {
  const int z = blockIdx.z;
  const float* __restrict__ W = (z == 0) ? W0 : (z == 1) ? W1 : (z == 2) ? W2 : W3;
  unsigned short* __restrict__ dst = (z < 3) ? (Wt + (size_t)z * 1024 * 1024) : Wot;
  __shared__ float tile[32][33];
  const int tx = threadIdx.x, ty = threadIdx.y;
  const int bx = blockIdx.x * 32, by = blockIdx.y * 32;
#pragma unroll
  for (int i = 0; i < 4; ++i)
    tile[ty + 8 * i][tx] = W[(size_t)(by + ty + 8 * i) * 1024 + bx + tx];
  __syncthreads();
#pragma unroll
  for (int i = 0; i < 4; ++i)
    dst[(size_t)(bx + ty + 8 * i) * 1024 + by + tx] = f2b(tile[tx][ty + 8 * i]);
}

// ---------------- QKV GEMM (M=8192,N=3072,K=1024) + fused RoPE/RMS epilogue ----------------
// BK=32, 4-slot LDS rotation, counted vmcnt(8) (no drain in steady state), raw s_barrier.
// 32-col rows (64B) are inherently bank-conflict-free for the frag reads (no swizzle).
// Prefetch distance 3 tiles; stage(t+3) overwrites slot consumed at tile t-1.
// Q pre-scaled by (1/sqrt(D)) * log2(e) so attention scores are in log2 domain.
__global__ __launch_bounds__(256) void gemm_qkv(
    const unsigned short* __restrict__ A, const unsigned short* __restrict__ Bt,
    unsigned short* __restrict__ Qr, unsigned short* __restrict__ Kr,
    unsigned short* __restrict__ Vr,
    const float* __restrict__ cosp, const float* __restrict__ sinp) {
  __shared__ unsigned short As[4 * 128 * 32];  // 4 slots x 8KB
  __shared__ unsigned short Bs[4 * 128 * 32];
  const int tid = threadIdx.x;
  const int wave = tid >> 6, lane = tid & 63;
  const int ln = lane & 15, grp = lane >> 4;
  const int wr = wave >> 1, wc = wave & 1;
  const int row0 = blockIdx.x * 128, col0 = blockIdx.y * 128;

  f32x4 acc[4][4];
  const f32x4 z4 = {0.f, 0.f, 0.f, 0.f};
#pragma unroll
  for (int m = 0; m < 4; ++m)
#pragma unroll
    for (int n = 0; n < 4; ++n) acc[m][n] = z4;

  auto stage = [&](int t) {  // 4 glds/thread: tile t (k = t*32..+32) -> slot t&3
    const int slot = t & 3;
    char* Adst = (char*)As + slot * 8192;
    char* Bdst = (char*)Bs + slot * 8192;
    const int kbase = t * 32;
#pragma unroll
    for (int p = 0; p < 2; ++p) {
      const int cl = p * 256 + tid;          // 16B chunk 0..511 (128 rows x 4)
      const int r = cl >> 2;
      const int cc = (cl & 3) * 8;
      glds16(A + (long)(row0 + r) * 1024 + kbase + cc, Adst + p * 4096 + wave * 1024);
      glds16(Bt + (long)(col0 + r) * 1024 + kbase + cc, Bdst + p * 4096 + wave * 1024);
    }
  };

  stage(0); stage(1); stage(2);
  for (int t = 0; t < 32; ++t) {
    // tiles t+1, t+2 may be in flight (8 loads); tile t must have landed.
    if (t <= 29)      asm volatile("s_waitcnt vmcnt(8)" ::: "memory");
    else if (t == 30) asm volatile("s_waitcnt vmcnt(4)" ::: "memory");
    else              asm volatile("s_waitcnt vmcnt(0)" ::: "memory");
    __builtin_amdgcn_s_barrier();
    if (t + 3 < 32) stage(t + 3);   // slot (t+3)&3 == (t-1)&3: consumed before barrier

    const unsigned short* Asl = As + (t & 3) * 4096;
    const unsigned short* Bsl = Bs + (t & 3) * 4096;
    short8 af[4], bfv[4];
#pragma unroll
    for (int m = 0; m < 4; ++m)
      af[m] = *(const short8*)&Asl[(wr * 64 + m * 16 + ln) * 32 + grp * 8];
#pragma unroll
    for (int n = 0; n < 4; ++n)
      bfv[n] = *(const short8*)&Bsl[(wc * 64 + n * 16 + ln) * 32 + grp * 8];
    __builtin_amdgcn_s_setprio(1);
#pragma unroll
    for (int m = 0; m < 4; ++m)
#pragma unroll
      for (int n = 0; n < 4; ++n)
        acc[m][n] = mfma16(af[m], bfv[n], acc[m][n]);
    __builtin_amdgcn_s_setprio(0);
  }

  const int colbase = col0 + wc * 64;
  const int z = colbase >> 10;
  const int h = (colbase & 1023) >> 6;
  unsigned short* __restrict__ dst = (z == 0) ? Qr : (z == 1) ? Kr : Vr;

  if (z < 2) {  // RoPE + RMS-norm for Q,K (Q pre-scaled: 0.125 * log2(e))
    const float qs = (z == 0) ? 0.125f * 1.44269504f : 1.0f;
#pragma unroll
    for (int m = 0; m < 4; ++m) {
#pragma unroll
      for (int reg = 0; reg < 4; ++reg) {
        const int row = row0 + wr * 64 + m * 16 + grp * 4 + reg;
        const int t = row & 2047, b = row >> 11;
        const float u0 = acc[m][0][reg], u1 = acc[m][1][reg];
        const float u2 = acc[m][2][reg], u3 = acc[m][3][reg];
        const float c0 = cosp[t * 32 + ln],      s0 = sinp[t * 32 + ln];
        const float c1 = cosp[t * 32 + 16 + ln], s1 = sinp[t * 32 + 16 + ln];
        const float r0 =  u0 * c0 + u2 * s0;
        const float r1 =  u1 * c1 + u3 * s1;
        const float r2 = -u0 * s0 + u2 * c0;
        const float r3 = -u1 * s1 + u3 * c1;
        float ss = r0 * r0 + r1 * r1 + r2 * r2 + r3 * r3;
        ss += __shfl_xor(ss, 1); ss += __shfl_xor(ss, 2);
        ss += __shfl_xor(ss, 4); ss += __shfl_xor(ss, 8);
        const float inv = rsqrtf(ss * (1.0f / 64.0f) + 1.1920929e-07f) * qs;
        const long base = (((long)(b * 16 + h)) * 2048 + t) * 64;
        dst[base + ln]      = f2b(r0 * inv);
        dst[base + 16 + ln] = f2b(r1 * inv);
        dst[base + 32 + ln] = f2b(r2 * inv);
        dst[base + 48 + ln] = f2b(r3 * inv);
      }
    }
  } else {  // plain relayout for V
#pragma unroll
    for (int m = 0; m < 4; ++m) {
#pragma unroll
      for (int reg = 0; reg < 4; ++reg) {
        const int row = row0 + wr * 64 + m * 16 + grp * 4 + reg;
        const int t = row & 2047, b = row >> 11;
        const long base = (((long)(b * 16 + h)) * 2048 + t) * 64;
#pragma unroll
        for (int n = 0; n < 4; ++n)
          dst[base + n * 16 + ln] = f2b(acc[m][n][reg]);
      }
    }
  }
}

// ---------------- causal flash attention (r9: staged K+V, fixed-max, ones-MFMA l) -------
// Q/K/V: bf16 [B*H][T][64]; Y: bf16 [B][T][H][64]
// Fixed-max softmax (RMS-norm bounds |s_log2| <= 11.6): P = exp2(s) raw, no shift.
// l accumulated on the MATRIX pipe: extra MFMA with A = ones => D[r][q] = sum_kv P.
// 1024 blocks, 64-row q-tiles paired {bx, 31-bx} => uniform 33 kv-iters/block.
__global__ __launch_bounds__(256) void attn_kernel(
    const unsigned short* __restrict__ Q, const unsigned short* __restrict__ K,
    const unsigned short* __restrict__ V, unsigned short* __restrict__ Y) {
  // per buffer (u16): K [64][64] XOR-swizzled (8KB) | V subtiled [dt4][kvt16][4][16] (8KB)
  __shared__ unsigned short lds[2 * 8192];
  const int tid = threadIdx.x;
  const int wave = tid >> 6, lane = tid & 63;
  const int ln = lane & 15, grp = lane >> 4;

  const int linb = blockIdx.x;            // 1024 blocks
  const int xcd = linb & 7, slot = linb >> 3;
  const int bh = xcd * 8 + (slot >> 4);   // 8 heads per XCD => K/V L2-resident
  const int pr = slot & 15;               // 16 tile-pairs per bh

  const long bhT = (long)bh * 2048;
  const int b = bh >> 4, h = bh & 15;
  auto* lds3 = (__attribute__((address_space(3))) unsigned short*)lds;

  const short o1 = (short)0x3f80;  // bf16 1.0
  const short8 ones = {o1, o1, o1, o1, o1, o1, o1, o1};

  auto stage = [&](int j, int buf) {
    const long kvoff = bhT + (long)j * 64;
    char* Kb = (char*)lds + buf * 16384;
#pragma unroll
    for (int p = 0; p < 2; ++p) {
      const int cl = p * 256 + tid;                      // 16B chunk id 0..511
      const int krow = cl >> 3;
      const int kcb = ((cl & 7) * 16) ^ ((krow & 7) << 4);
      glds16(K + (kvoff + krow) * 64 + (kcb >> 1), Kb + p * 4096 + wave * 1024);
      const int dtv = cl >> 7, kvt = (cl >> 3) & 15, rr = (cl >> 1) & 3, hf = cl & 1;
      glds16(V + (kvoff + kvt * 4 + rr) * 64 + dtv * 16 + hf * 8,
             Kb + 8192 + p * 4096 + wave * 1024);
    }
  };

  const f32x4 z4 = {0.f, 0.f, 0.f, 0.f};

  for (int half = 0; half < 2; ++half) {
    const int bx = (half == 0) ? pr : 31 - pr;   // 64-row q-tile index
    const int qw = bx * 64 + wave * 16;          // this wave's 16 q-rows
    const int jmax = bx;                         // kv tiles 0..bx; only j==bx masked

    short8 qf[2];
#pragma unroll
    for (int c = 0; c < 2; ++c)
      qf[c] = *(const short8*)(Q + (bhT + qw + ln) * 64 + c * 32 + grp * 8);

    f32x4 accO[4];
#pragma unroll
    for (int dt = 0; dt < 4; ++dt) accO[dt] = z4;
    f32x4 accL = z4;   // l accumulator: lane's reg0 ends with l for q=ln

    stage(0, 0);
    asm volatile("s_waitcnt vmcnt(0)" ::: "memory");
    __builtin_amdgcn_s_barrier();

    int cur = 0;
    for (int j = 0; j <= jmax; ++j, cur ^= 1) {
      if (j < jmax) {
        stage(j + 1, cur ^ 1);
        asm volatile("s_waitcnt vmcnt(4)" ::: "memory");
      } else {
        asm volatile("s_waitcnt vmcnt(0)" ::: "memory");
      }
      __builtin_amdgcn_s_barrier();

      const unsigned short* Kb = lds + cur * 8192;
      const bool maskp = (j == jmax);

      // S^T = K * Q^T : lane holds S^T[kv=ct*16+grp*4+r][q=ln] (log2 domain)
      f32x4 sacc[4];
#pragma unroll
      for (int ct = 0; ct < 4; ++ct) sacc[ct] = z4;
      __builtin_amdgcn_s_setprio(1);
#pragma unroll
      for (int ct = 0; ct < 4; ++ct) {
        const int row = ct * 16 + ln;
        const int sw = (ln & 7) << 4;
        const char* rp = (const char*)Kb + row * 128;
        const short8 kf0 = *(const short8*)(rp + ((grp * 16) ^ sw));
        const short8 kf1 = *(const short8*)(rp + ((grp * 16 + 64) ^ sw));
        sacc[ct] = mfma16(kf0, qf[0], sacc[ct]);
        sacc[ct] = mfma16(kf1, qf[1], sacc[ct]);
      }
      __builtin_amdgcn_s_setprio(0);

      // fixed-max softmax: P = exp2(s) raw (s <= 11.6 => P <= ~3200, bf16-safe);
      // masked lanes -> exp2(-inf) = 0. No shift, no reduction (l via MFMA below).
      short8 pf[2];
      {
        if (maskp) {
          const int q = qw + ln;
#pragma unroll
          for (int ct = 0; ct < 4; ++ct)
#pragma unroll
            for (int r = 0; r < 4; ++r) {
              const int kv = j * 64 + ct * 16 + grp * 4 + r;
              if (kv > q) sacc[ct][r] = -INFINITY;
            }
        }
#pragma unroll
        for (int ct = 0; ct < 4; ++ct)
#pragma unroll
          for (int r = 0; r < 4; ++r)
            pf[ct >> 1][(ct & 1) * 4 + r] = (short)b16(exp2f(sacc[ct][r]));
      }

      // O^T += V^T * P^T ; V^T A-frags via hardware transpose-read.
      // "=&v" early-clobber REQUIRED (async writeback must not alias the address).
      const unsigned vb = (unsigned)(size_t)&lds3[cur * 8192 + 4096] + (unsigned)lane * 8;
      short4v t[4][4];
#pragma unroll
      for (int dt = 0; dt < 4; ++dt) {
        const unsigned va = vb + dt * 2048;
        asm volatile("ds_read_b64_tr_b16 %0, %4 offset:0\n\t"
                     "ds_read_b64_tr_b16 %1, %4 offset:512\n\t"
                     "ds_read_b64_tr_b16 %2, %4 offset:1024\n\t"
                     "ds_read_b64_tr_b16 %3, %4 offset:1536"
                     : "=&v"(t[dt][0]), "=&v"(t[dt][1]), "=&v"(t[dt][2]), "=&v"(t[dt][3])
                     : "v"(va));
      }
      asm volatile("s_waitcnt lgkmcnt(0)" ::: "memory");
      __builtin_amdgcn_sched_barrier(0);
      __builtin_amdgcn_s_setprio(1);
#pragma unroll
      for (int dt = 0; dt < 4; ++dt) {
        const short8 vf0 = __builtin_shufflevector(t[dt][0], t[dt][1], 0, 1, 2, 3, 4, 5, 6, 7);
        const short8 vf1 = __builtin_shufflevector(t[dt][2], t[dt][3], 0, 1, 2, 3, 4, 5, 6, 7);
        accO[dt] = mfma16(vf0, pf[0], accO[dt]);
        accO[dt] = mfma16(vf1, pf[1], accO[dt]);
      }
      accL = mfma16(ones, pf[0], accL);   // l_q = sum_kv P[kv][q]
      accL = mfma16(ones, pf[1], accL);
      __builtin_amdgcn_s_setprio(0);
      __builtin_amdgcn_s_barrier();
    }

    // epilogue: Y[b][t][h][d]; lane holds O^T[d=dt*16+grp*4+r][q=ln of tile];
    // accL[0] already holds this lane's q-column denominator (no cross-lane reduce).
    {
      const float inv = 1.0f / accL[0];
      const int t_ = qw + ln;
      const long base = (((long)(b * 2048 + t_)) * 16 + h) * 64;
#pragma unroll
      for (int dt = 0; dt < 4; ++dt) {
        unsigned short o[4];
#pragma unroll
        for (int r = 0; r < 4; ++r) o[r] = b16(accO[dt][r] * inv);
        *(short4v*)(Y + base + dt * 16 + grp * 4) = *(const short4v*)o;
      }
    }
  }
}

// ---------------- output GEMM (M=8192,N=1024,K=1024), f32 out ----------------
// Same BK=32 / 4-slot / counted-vmcnt structure as gemm_qkv.
__global__ __launch_bounds__(256) void gemm_out(
    const unsigned short* __restrict__ A, const unsigned short* __restrict__ Bt,
    float* __restrict__ C) {
  __shared__ unsigned short As[4 * 128 * 32];
  __shared__ unsigned short Bs[4 * 128 * 32];
  const int tid = threadIdx.x;
  const int wave = tid >> 6, lane = tid & 63;
  const int ln = lane & 15, grp = lane >> 4;
  const int wr = wave >> 1, wc = wave & 1;
  const int row0 = blockIdx.x * 128, col0 = blockIdx.y * 128;

  f32x4 acc[4][4];
  const f32x4 z4 = {0.f, 0.f, 0.f, 0.f};
#pragma unroll
  for (int m = 0; m < 4; ++m)
#pragma unroll
    for (int n = 0; n < 4; ++n) acc[m][n] = z4;

  auto stage = [&](int t) {
    const int slot = t & 3;
    char* Adst = (char*)As + slot * 8192;
    char* Bdst = (char*)Bs + slot * 8192;
    const int kbase = t * 32;
#pragma unroll
    for (int p = 0; p < 2; ++p) {
      const int cl = p * 256 + tid;
      const int r = cl >> 2;
      const int cc = (cl & 3) * 8;
      glds16(A + (long)(row0 + r) * 1024 + kbase + cc, Adst + p * 4096 + wave * 1024);
      glds16(Bt + (long)(col0 + r) * 1024 + kbase + cc, Bdst + p * 4096 + wave * 1024);
    }
  };

  stage(0); stage(1); stage(2);
  for (int t = 0; t < 32; ++t) {
    if (t <= 29)      asm volatile("s_waitcnt vmcnt(8)" ::: "memory");
    else if (t == 30) asm volatile("s_waitcnt vmcnt(4)" ::: "memory");
    else              asm volatile("s_waitcnt vmcnt(0)" ::: "memory");
    __builtin_amdgcn_s_barrier();
    if (t + 3 < 32) stage(t + 3);

    const unsigned short* Asl = As + (t & 3) * 4096;
    const unsigned short* Bsl = Bs + (t & 3) * 4096;
    short8 af[4], bfv[4];
#pragma unroll
    for (int m = 0; m < 4; ++m)
      af[m] = *(const short8*)&Asl[(wr * 64 + m * 16 + ln) * 32 + grp * 8];
#pragma unroll
    for (int n = 0; n < 4; ++n)
      bfv[n] = *(const short8*)&Bsl[(wc * 64 + n * 16 + ln) * 32 + grp * 8];
    __builtin_amdgcn_s_setprio(1);
#pragma unroll
    for (int m = 0; m < 4; ++m)
#pragma unroll
      for (int n = 0; n < 4; ++n)
        acc[m][n] = mfma16(af[m], bfv[n], acc[m][n]);
    __builtin_amdgcn_s_setprio(0);
  }

#pragma unroll
  for (int m = 0; m < 4; ++m)
#pragma unroll
    for (int reg = 0; reg < 4; ++reg) {
      const int row = row0 + wr * 64 + m * 16 + grp * 4 + reg;
#pragma unroll
      for (int n = 0; n < 4; ++n)
        C[(long)row * 1024 + col0 + wc * 64 + n * 16 + ln] = acc[m][n][reg];
    }
}

extern "C" void kernel_launch(void* const* d_in, const int* in_sizes, int n_in,
                              void* d_out, int out_size, void* d_ws, size_t ws_size,
                              hipStream_t stream) {
  (void)in_sizes; (void)n_in; (void)out_size; (void)ws_size;
  const float* x    = (const float*)d_in[0];
  const float* cosp = (const float*)d_in[1];
  const float* sinp = (const float*)d_in[2];
  const float* Wq   = (const float*)d_in[3];
  const float* Wk   = (const float*)d_in[4];
  const float* Wv   = (const float*)d_in[5];
  const float* Wo   = (const float*)d_in[6];
  float* out = (float*)d_out;

  unsigned short* xb  = (unsigned short*)d_ws;
  unsigned short* Wt  = xb  + (size_t)8192 * 1024;
  unsigned short* Wot = Wt  + (size_t)3 * 1024 * 1024;
  unsigned short* Qr  = Wot + (size_t)1024 * 1024;
  unsigned short* Kr  = Qr  + (size_t)8192 * 1024;
  unsigned short* Vr  = Kr  + (size_t)8192 * 1024;
  unsigned short* Yb  = xb;  // xb dead after gemm_qkv

  cast_x_kernel<<<4096, 256, 0, stream>>>(x, xb);
  transpose_cast_w<<<dim3(32, 32, 4), dim3(32, 8), 0, stream>>>(Wq, Wk, Wv, Wo, Wt, Wot);
  gemm_qkv<<<dim3(64, 24), 256, 0, stream>>>(xb, Wt, Qr, Kr, Vr, cosp, sinp);
  attn_kernel<<<1024, 256, 0, stream>>>(Qr, Kr, Vr, Yb);
  gemm_out<<<dim3(64, 8), 256, 0, stream>>>(Yb, Wot, out);
}

// Round 14
// 189.251 us; speedup vs baseline: 1.0253x; 1.0253x over previous
//
#include <hip/hip_runtime.h>

// B=4 T=2048 C=1024 H=16 D=64  N=B*T=8192

typedef __attribute__((ext_vector_type(8))) short short8;
typedef __attribute__((ext_vector_type(4))) short short4v;
typedef __attribute__((ext_vector_type(4))) float f32x4;

__device__ __forceinline__ unsigned short f2b(float f) {
  union { float f; unsigned int i; } x; x.f = f;
  return (unsigned short)((x.i + 0x7FFFu + ((x.i >> 16) & 1u)) >> 16);
}

// hardware RNE f32->bf16
__device__ __forceinline__ unsigned short b16(float f) {
  return __builtin_bit_cast(unsigned short, (__bf16)f);
}

__device__ __forceinline__ void glds16(const void* g, void* l) {
  __builtin_amdgcn_global_load_lds((const __attribute__((address_space(1))) unsigned int*)g,
                                   (__attribute__((address_space(3))) unsigned int*)l,
                                   16, 0, 0);
}

__device__ __forceinline__ f32x4 mfma16(short8 a, short8 b, f32x4 c) {
  return __builtin_amdgcn_mfma_f32_16x16x32_bf16(a, b, c, 0, 0, 0);
}

// ---------------- cast x: f32 -> bf16, 8 elems/thread ----------------
__global__ __launch_bounds__(256) void cast_x_kernel(const float* __restrict__ x,
                                                     unsigned short* __restrict__ xb) {
  const long i = ((long)blockIdx.x * 256 + threadIdx.x) * 8;
  const float4 a = *(const float4*)(x + i);
  const float4 b = *(const float4*)(x + i + 4);
  unsigned short o[8] = {f2b(a.x), f2b(a.y), f2b(a.z), f2b(a.w),
                         f2b(b.x), f2b(b.y), f2b(b.z), f2b(b.w)};
  *(short8*)(xb + i) = *(const short8*)o;
}

// ---------------- transpose+cast weights: dst[n][k] = W[k][n] ----------------
__global__ __launch_bounds__(256) void transpose_cast_w(
    const float* __restrict__ W0, const float* __restrict__ W1,
    const float* __restrict__ W2, const float* __restrict__ W3,
    unsigned short* __restrict__ Wt, unsigned short* __restrict__ Wot) {
  const int z = blockIdx.z;
  const float* __restrict__ W = (z == 0) ? W0 : (z == 1) ? W1 : (z == 2) ? W2 : W3;
  unsigned short* __restrict__ dst = (z < 3) ? (Wt + (size_t)z * 1024 * 1024) : Wot;
  __shared__ float tile[32][33];
  const int tx = threadIdx.x, ty = threadIdx.y;
  const int bx = blockIdx.x * 32, by = blockIdx.y * 32;
#pragma unroll
  for (int i = 0; i < 4; ++i)
    tile[ty + 8 * i][tx] = W[(size_t)(by + ty + 8 * i) * 1024 + bx + tx];
  __syncthreads();
#pragma unroll
  for (int i = 0; i < 4; ++i)
    dst[(size_t)(bx + ty + 8 * i) * 1024 + by + tx] = f2b(tile[tx][ty + 8 * i]);
}

// ---------------- QKV GEMM: 256^2 tile, 8 waves, 8-phase counted-vmcnt pipeline ---------
// M=8192, N=3072, K=1024. BK=64. LDS 128KB: 2 buffers x {A,B} x 2 half-tiles [128][64].
// Half-tile rows are 128B => r7-proven XOR swizzle (stage chunk c^(r&7), read ^(ln&7)<<4)
// gives conflict-free ds_read_b128. Phases: stage 1 half-tile -> other buffer; vmcnt(2)
// only at phases 0/4 (counted, loads stay in flight); barrier; 12 ds_read; 16 MFMA
// (one C-quadrant x K=64). Hazards: stage(kt+1)->buf1 during phases 0-3 (buf1 last read
// prev iter phases 4-7, sealed by iter-end barrier); stage(kt+2)->buf0 during phases 4-7
// (buf0 reads sealed by mid-iter barrier). Per-element K order identical to BK=64 loop.
// Q pre-scaled by (1/sqrt(D)) * log2(e) in the fused RoPE/RMS epilogue.
__global__ __launch_bounds__(512, 2) void gemm_qkv(
    const unsigned short* __restrict__ A, const unsigned short* __restrict__ Bt,
    unsigned short* __restrict__ Qr, unsigned short* __restrict__ Kr,
    unsigned short* __restrict__ Vr,
    const float* __restrict__ cosp, const float* __restrict__ sinp) {
  __shared__ unsigned short As[2][2][128 * 64];  // [buf][half], 16KB each
  __shared__ unsigned short Bs[2][2][128 * 64];
  const int tid = threadIdx.x;
  const int wave = tid >> 6, lane = tid & 63;
  const int ln = lane & 15, grp = lane >> 4;
  const int wr = wave >> 2, wc = wave & 3;         // 2x4 wave grid; 128x64 out/wave
  const int row0 = blockIdx.x * 256, col0 = blockIdx.y * 256;
  const int sw = (ln & 7) << 4;

  f32x4 acc[8][4];
  const f32x4 z4 = {0.f, 0.f, 0.f, 0.f};
#pragma unroll
  for (int m = 0; m < 8; ++m)
#pragma unroll
    for (int n = 0; n < 4; ++n) acc[m][n] = z4;

  auto stageA = [&](int kt, int half) {
    unsigned short* dst = As[kt & 1][half];
#pragma unroll
    for (int p = 0; p < 2; ++p) {
      const int cl = p * 512 + tid;                 // 16B chunk 0..1023
      const int r = cl >> 3;                        // half-tile row 0..127
      const int sc = ((cl & 7) ^ (r & 7)) * 8;      // pre-swizzled source col
      glds16(A + (long)(row0 + half * 128 + r) * 1024 + kt * 64 + sc,
             (char*)dst + p * 8192 + wave * 1024);
    }
  };
  auto stageB = [&](int kt, int half) {
    unsigned short* dst = Bs[kt & 1][half];
#pragma unroll
    for (int p = 0; p < 2; ++p) {
      const int cl = p * 512 + tid;
      const int r = cl >> 3;
      const int sc = ((cl & 7) ^ (r & 7)) * 8;
      glds16(Bt + (long)(col0 + half * 128 + r) * 1024 + kt * 64 + sc,
             (char*)dst + p * 8192 + wave * 1024);
    }
  };

  auto phase = [&](int buf, int q) {  // q: C-quadrant (mh = q>>1, nh = q&1)
    const int mh = q >> 1, nh = q & 1;
    const unsigned short* Ah = As[buf][wr];
    const unsigned short* Bh = Bs[buf][wc >> 1];
    short8 af[4][2], bf[2][2];
#pragma unroll
    for (int i = 0; i < 4; ++i) {
      const int row = (mh * 4 + i) * 16 + ln;
      const char* rp = (const char*)Ah + row * 128;
      af[i][0] = *(const short8*)(rp + ((grp * 16) ^ sw));
      af[i][1] = *(const short8*)(rp + ((grp * 16 + 64) ^ sw));
    }
#pragma unroll
    for (int j = 0; j < 2; ++j) {
      const int row = (wc & 1) * 64 + (nh * 2 + j) * 16 + ln;
      const char* rp = (const char*)Bh + row * 128;
      bf[j][0] = *(const short8*)(rp + ((grp * 16) ^ sw));
      bf[j][1] = *(const short8*)(rp + ((grp * 16 + 64) ^ sw));
    }
    __builtin_amdgcn_s_setprio(1);
#pragma unroll
    for (int i = 0; i < 4; ++i)
#pragma unroll
      for (int j = 0; j < 2; ++j) {
        const int m = mh * 4 + i, n = nh * 2 + j;
        acc[m][n] = mfma16(af[i][0], bf[j][0], acc[m][n]);
        acc[m][n] = mfma16(af[i][1], bf[j][1], acc[m][n]);
      }
    __builtin_amdgcn_s_setprio(0);
  };

  // prologue: K-tile 0 -> buf0, full drain once
  stageA(0, 0); stageA(0, 1); stageB(0, 0); stageB(0, 1);
  asm volatile("s_waitcnt vmcnt(0)" ::: "memory");
  __builtin_amdgcn_s_barrier();

  for (int it = 0; it < 8; ++it) {
    const int kt = 2 * it;
    // phases 0-3: compute kt (buf0); stage kt+1 -> buf1
#pragma unroll
    for (int q = 0; q < 4; ++q) {
      if (q == 0) {
        stageA(kt + 1, 0);
        asm volatile("s_waitcnt vmcnt(2)" ::: "memory");  // kt fully resident
      } else if (q == 1) stageA(kt + 1, 1);
      else if (q == 2)  stageB(kt + 1, 0);
      else              stageB(kt + 1, 1);
      __builtin_amdgcn_s_barrier();
      phase(0, q);
    }
    __builtin_amdgcn_s_barrier();  // seal buf0 reads before phases 4-7 stage into buf0
    // phases 4-7: compute kt+1 (buf1); stage kt+2 -> buf0
#pragma unroll
    for (int q = 0; q < 4; ++q) {
      if (q == 0) {
        if (it < 7) {
          stageA(kt + 2, 0);
          asm volatile("s_waitcnt vmcnt(2)" ::: "memory");  // kt+1 fully resident
        } else {
          asm volatile("s_waitcnt vmcnt(0)" ::: "memory");
        }
      } else if (it < 7) {
        if (q == 1)      stageA(kt + 2, 1);
        else if (q == 2) stageB(kt + 2, 0);
        else             stageB(kt + 2, 1);
      }
      __builtin_amdgcn_s_barrier();
      phase(1, q);
    }
    __builtin_amdgcn_s_barrier();  // seal buf1 reads before next iter stages into buf1
  }

  // fused epilogue: each wave's 64-col block (wc) = one head of q/k/v
  const int colbase = col0 + wc * 64;
  const int z = colbase >> 10;
  const int h = (colbase & 1023) >> 6;
  unsigned short* __restrict__ dst = (z == 0) ? Qr : (z == 1) ? Kr : Vr;

  if (z < 2) {  // RoPE + RMS-norm for Q,K (Q pre-scaled: 0.125 * log2(e))
    const float qs = (z == 0) ? 0.125f * 1.44269504f : 1.0f;
#pragma unroll
    for (int m = 0; m < 8; ++m) {
#pragma unroll
      for (int reg = 0; reg < 4; ++reg) {
        const int row = row0 + wr * 128 + m * 16 + grp * 4 + reg;
        const int t = row & 2047, b = row >> 11;
        const float u0 = acc[m][0][reg], u1 = acc[m][1][reg];
        const float u2 = acc[m][2][reg], u3 = acc[m][3][reg];
        const float c0 = cosp[t * 32 + ln],      s0 = sinp[t * 32 + ln];
        const float c1 = cosp[t * 32 + 16 + ln], s1 = sinp[t * 32 + 16 + ln];
        const float r0 =  u0 * c0 + u2 * s0;
        const float r1 =  u1 * c1 + u3 * s1;
        const float r2 = -u0 * s0 + u2 * c0;
        const float r3 = -u1 * s1 + u3 * c1;
        float ss = r0 * r0 + r1 * r1 + r2 * r2 + r3 * r3;
        ss += __shfl_xor(ss, 1); ss += __shfl_xor(ss, 2);
        ss += __shfl_xor(ss, 4); ss += __shfl_xor(ss, 8);
        const float inv = rsqrtf(ss * (1.0f / 64.0f) + 1.1920929e-07f) * qs;
        const long base = (((long)(b * 16 + h)) * 2048 + t) * 64;
        dst[base + ln]      = f2b(r0 * inv);
        dst[base + 16 + ln] = f2b(r1 * inv);
        dst[base + 32 + ln] = f2b(r2 * inv);
        dst[base + 48 + ln] = f2b(r3 * inv);
      }
    }
  } else {  // plain relayout for V
#pragma unroll
    for (int m = 0; m < 8; ++m) {
#pragma unroll
      for (int reg = 0; reg < 4; ++reg) {
        const int row = row0 + wr * 128 + m * 16 + grp * 4 + reg;
        const int t = row & 2047, b = row >> 11;
        const long base = (((long)(b * 16 + h)) * 2048 + t) * 64;
#pragma unroll
        for (int n = 0; n < 4; ++n)
          dst[base + n * 16 + ln] = f2b(acc[m][n][reg]);
      }
    }
  }
}

// ---------------- causal flash attention (r9: staged K+V, fixed-max, ones-MFMA l) -------
// Q/K/V: bf16 [B*H][T][64]; Y: bf16 [B][T][H][64]
// Fixed-max softmax (RMS-norm bounds |s_log2| <= 11.6): P = exp2(s) raw, no shift.
// l accumulated on the MATRIX pipe: extra MFMA with A = ones => D[r][q] = sum_kv P.
// 1024 blocks, 64-row q-tiles paired {bx, 31-bx} => uniform 33 kv-iters/block.
__global__ __launch_bounds__(256) void attn_kernel(
    const unsigned short* __restrict__ Q, const unsigned short* __restrict__ K,
    const unsigned short* __restrict__ V, unsigned short* __restrict__ Y) {
  // per buffer (u16): K [64][64] XOR-swizzled (8KB) | V subtiled [dt4][kvt16][4][16] (8KB)
  __shared__ unsigned short lds[2 * 8192];
  const int tid = threadIdx.x;
  const int wave = tid >> 6, lane = tid & 63;
  const int ln = lane & 15, grp = lane >> 4;

  const int linb = blockIdx.x;            // 1024 blocks
  const int xcd = linb & 7, slot = linb >> 3;
  const int bh = xcd * 8 + (slot >> 4);   // 8 heads per XCD => K/V L2-resident
  const int pr = slot & 15;               // 16 tile-pairs per bh

  const long bhT = (long)bh * 2048;
  const int b = bh >> 4, h = bh & 15;
  auto* lds3 = (__attribute__((address_space(3))) unsigned short*)lds;

  const short o1 = (short)0x3f80;  // bf16 1.0
  const short8 ones = {o1, o1, o1, o1, o1, o1, o1, o1};

  auto stage = [&](int j, int buf) {
    const long kvoff = bhT + (long)j * 64;
    char* Kb = (char*)lds + buf * 16384;
#pragma unroll
    for (int p = 0; p < 2; ++p) {
      const int cl = p * 256 + tid;                      // 16B chunk id 0..511
      const int krow = cl >> 3;
      const int kcb = ((cl & 7) * 16) ^ ((krow & 7) << 4);
      glds16(K + (kvoff + krow) * 64 + (kcb >> 1), Kb + p * 4096 + wave * 1024);
      const int dtv = cl >> 7, kvt = (cl >> 3) & 15, rr = (cl >> 1) & 3, hf = cl & 1;
      glds16(V + (kvoff + kvt * 4 + rr) * 64 + dtv * 16 + hf * 8,
             Kb + 8192 + p * 4096 + wave * 1024);
    }
  };

  const f32x4 z4 = {0.f, 0.f, 0.f, 0.f};

  for (int half = 0; half < 2; ++half) {
    const int bx = (half == 0) ? pr : 31 - pr;   // 64-row q-tile index
    const int qw = bx * 64 + wave * 16;          // this wave's 16 q-rows
    const int jmax = bx;                         // kv tiles 0..bx; only j==bx masked

    short8 qf[2];
#pragma unroll
    for (int c = 0; c < 2; ++c)
      qf[c] = *(const short8*)(Q + (bhT + qw + ln) * 64 + c * 32 + grp * 8);

    f32x4 accO[4];
#pragma unroll
    for (int dt = 0; dt < 4; ++dt) accO[dt] = z4;
    f32x4 accL = z4;   // l accumulator: lane's reg0 ends with l for q=ln

    stage(0, 0);
    asm volatile("s_waitcnt vmcnt(0)" ::: "memory");
    __builtin_amdgcn_s_barrier();

    int cur = 0;
    for (int j = 0; j <= jmax; ++j, cur ^= 1) {
      if (j < jmax) {
        stage(j + 1, cur ^ 1);
        asm volatile("s_waitcnt vmcnt(4)" ::: "memory");
      } else {
        asm volatile("s_waitcnt vmcnt(0)" ::: "memory");
      }
      __builtin_amdgcn_s_barrier();

      const unsigned short* Kb = lds + cur * 8192;
      const bool maskp = (j == jmax);

      // S^T = K * Q^T : lane holds S^T[kv=ct*16+grp*4+r][q=ln] (log2 domain)
      f32x4 sacc[4];
#pragma unroll
      for (int ct = 0; ct < 4; ++ct) sacc[ct] = z4;
      __builtin_amdgcn_s_setprio(1);
#pragma unroll
      for (int ct = 0; ct < 4; ++ct) {
        const int row = ct * 16 + ln;
        const int sw = (ln & 7) << 4;
        const char* rp = (const char*)Kb + row * 128;
        const short8 kf0 = *(const short8*)(rp + ((grp * 16) ^ sw));
        const short8 kf1 = *(const short8*)(rp + ((grp * 16 + 64) ^ sw));
        sacc[ct] = mfma16(kf0, qf[0], sacc[ct]);
        sacc[ct] = mfma16(kf1, qf[1], sacc[ct]);
      }
      __builtin_amdgcn_s_setprio(0);

      // fixed-max softmax: P = exp2(s) raw (s <= 11.6 => P <= ~3200, bf16-safe);
      // masked lanes -> exp2(-inf) = 0. No shift, no reduction (l via MFMA below).
      short8 pf[2];
      {
        if (maskp) {
          const int q = qw + ln;
#pragma unroll
          for (int ct = 0; ct < 4; ++ct)
#pragma unroll
            for (int r = 0; r < 4; ++r) {
              const int kv = j * 64 + ct * 16 + grp * 4 + r;
              if (kv > q) sacc[ct][r] = -INFINITY;
            }
        }
#pragma unroll
        for (int ct = 0; ct < 4; ++ct)
#pragma unroll
          for (int r = 0; r < 4; ++r)
            pf[ct >> 1][(ct & 1) * 4 + r] = (short)b16(exp2f(sacc[ct][r]));
      }

      // O^T += V^T * P^T ; V^T A-frags via hardware transpose-read.
      // "=&v" early-clobber REQUIRED (async writeback must not alias the address).
      const unsigned vb = (unsigned)(size_t)&lds3[cur * 8192 + 4096] + (unsigned)lane * 8;
      short4v t[4][4];
#pragma unroll
      for (int dt = 0; dt < 4; ++dt) {
        const unsigned va = vb + dt * 2048;
        asm volatile("ds_read_b64_tr_b16 %0, %4 offset:0\n\t"
                     "ds_read_b64_tr_b16 %1, %4 offset:512\n\t"
                     "ds_read_b64_tr_b16 %2, %4 offset:1024\n\t"
                     "ds_read_b64_tr_b16 %3, %4 offset:1536"
                     : "=&v"(t[dt][0]), "=&v"(t[dt][1]), "=&v"(t[dt][2]), "=&v"(t[dt][3])
                     : "v"(va));
      }
      asm volatile("s_waitcnt lgkmcnt(0)" ::: "memory");
      __builtin_amdgcn_sched_barrier(0);
      __builtin_amdgcn_s_setprio(1);
#pragma unroll
      for (int dt = 0; dt < 4; ++dt) {
        const short8 vf0 = __builtin_shufflevector(t[dt][0], t[dt][1], 0, 1, 2, 3, 4, 5, 6, 7);
        const short8 vf1 = __builtin_shufflevector(t[dt][2], t[dt][3], 0, 1, 2, 3, 4, 5, 6, 7);
        accO[dt] = mfma16(vf0, pf[0], accO[dt]);
        accO[dt] = mfma16(vf1, pf[1], accO[dt]);
      }
      accL = mfma16(ones, pf[0], accL);   // l_q = sum_kv P[kv][q]
      accL = mfma16(ones, pf[1], accL);
      __builtin_amdgcn_s_setprio(0);
      __builtin_amdgcn_s_barrier();
    }

    // epilogue: Y[b][t][h][d]; lane holds O^T[d=dt*16+grp*4+r][q=ln of tile];
    // accL[0] already holds this lane's q-column denominator (no cross-lane reduce).
    {
      const float inv = 1.0f / accL[0];
      const int t_ = qw + ln;
      const long base = (((long)(b * 2048 + t_)) * 16 + h) * 64;
#pragma unroll
      for (int dt = 0; dt < 4; ++dt) {
        unsigned short o[4];
#pragma unroll
        for (int r = 0; r < 4; ++r) o[r] = b16(accO[dt][r] * inv);
        *(short4v*)(Y + base + dt * 16 + grp * 4) = *(const short4v*)o;
      }
    }
  }
}

// ---------------- output GEMM (M=8192,N=1024,K=1024), f32 out ----------------
// r7-form: BK=64, row-XOR-swizzled LDS, single-buffered.
__global__ __launch_bounds__(256) void gemm_out(
    const unsigned short* __restrict__ A, const unsigned short* __restrict__ Bt,
    float* __restrict__ C) {
  __shared__ unsigned short As[128 * 64];
  __shared__ unsigned short Bs[128 * 64];
  const int tid = threadIdx.x;
  const int wave = tid >> 6, lane = tid & 63;
  const int ln = lane & 15, grp = lane >> 4;
  const int wr = wave >> 1, wc = wave & 1;
  const int row0 = blockIdx.x * 128, col0 = blockIdx.y * 128;

  f32x4 acc[4][4];
  const f32x4 z4 = {0.f, 0.f, 0.f, 0.f};
#pragma unroll
  for (int m = 0; m < 4; ++m)
#pragma unroll
    for (int n = 0; n < 4; ++n) acc[m][n] = z4;

  const int sw = (ln & 7) << 4;

  for (int k0 = 0; k0 < 1024; k0 += 64) {
    __syncthreads();
#pragma unroll
    for (int it = 0; it < 4; ++it) {
      const int cl = it * 256 + tid;
      const int r = cl >> 3;
      const int sc = ((cl & 7) ^ (r & 7)) * 8;
      glds16(A + (long)(row0 + r) * 1024 + k0 + sc, (char*)As + it * 4096 + wave * 1024);
      glds16(Bt + (long)(col0 + r) * 1024 + k0 + sc, (char*)Bs + it * 4096 + wave * 1024);
    }
    __syncthreads();
#pragma unroll
    for (int ks = 0; ks < 2; ++ks) {
      short8 af[4], bfv[4];
#pragma unroll
      for (int m = 0; m < 4; ++m) {
        const int row = wr * 64 + m * 16 + ln;
        af[m] = *(const short8*)((const char*)As + row * 128 + ((grp * 16 + ks * 64) ^ sw));
      }
#pragma unroll
      for (int n = 0; n < 4; ++n) {
        const int row = wc * 64 + n * 16 + ln;
        bfv[n] = *(const short8*)((const char*)Bs + row * 128 + ((grp * 16 + ks * 64) ^ sw));
      }
#pragma unroll
      for (int m = 0; m < 4; ++m)
#pragma unroll
        for (int n = 0; n < 4; ++n)
          acc[m][n] = mfma16(af[m], bfv[n], acc[m][n]);
    }
  }

#pragma unroll
  for (int m = 0; m < 4; ++m)
#pragma unroll
    for (int reg = 0; reg < 4; ++reg) {
      const int row = row0 + wr * 64 + m * 16 + grp * 4 + reg;
#pragma unroll
      for (int n = 0; n < 4; ++n)
        C[(long)row * 1024 + col0 + wc * 64 + n * 16 + ln] = acc[m][n][reg];
    }
}

extern "C" void kernel_launch(void* const* d_in, const int* in_sizes, int n_in,
                              void* d_out, int out_size, void* d_ws, size_t ws_size,
                              hipStream_t stream) {
  (void)in_sizes; (void)n_in; (void)out_size; (void)ws_size;
  const float* x    = (const float*)d_in[0];
  const float* cosp = (const float*)d_in[1];
  const float* sinp = (const float*)d_in[2];
  const float* Wq   = (const float*)d_in[3];
  const float* Wk   = (const float*)d_in[4];
  const float* Wv   = (const float*)d_in[5];
  const float* Wo   = (const float*)d_in[6];
  float* out = (float*)d_out;

  unsigned short* xb  = (unsigned short*)d_ws;
  unsigned short* Wt  = xb  + (size_t)8192 * 1024;
  unsigned short* Wot = Wt  + (size_t)3 * 1024 * 1024;
  unsigned short* Qr  = Wot + (size_t)1024 * 1024;
  unsigned short* Kr  = Qr  + (size_t)8192 * 1024;
  unsigned short* Vr  = Kr  + (size_t)8192 * 1024;
  unsigned short* Yb  = xb;  // xb dead after gemm_qkv

  cast_x_kernel<<<4096, 256, 0, stream>>>(x, xb);
  transpose_cast_w<<<dim3(32, 32, 4), dim3(32, 8), 0, stream>>>(Wq, Wk, Wv, Wo, Wt, Wot);
  gemm_qkv<<<dim3(32, 12), 512, 0, stream>>>(xb, Wt, Qr, Kr, Vr, cosp, sinp);
  attn_kernel<<<1024, 256, 0, stream>>>(Qr, Kr, Vr, Yb);
  gemm_out<<<dim3(64, 8), 256, 0, stream>>>(Yb, Wot, out);
}

// Round 15
// 177.269 us; speedup vs baseline: 1.0946x; 1.0676x over previous
//
#include <hip/hip_runtime.h>

// B=4 T=2048 C=1024 H=16 D=64  N=B*T=8192

typedef __attribute__((ext_vector_type(8))) short short8;
typedef __attribute__((ext_vector_type(4))) short short4v;
typedef __attribute__((ext_vector_type(4))) float f32x4;

__device__ __forceinline__ unsigned short f2b(float f) {
  union { float f; unsigned int i; } x; x.f = f;
  return (unsigned short)((x.i + 0x7FFFu + ((x.i >> 16) & 1u)) >> 16);
}

// hardware RNE f32->bf16
__device__ __forceinline__ unsigned short b16(float f) {
  return __builtin_bit_cast(unsigned short, (__bf16)f);
}

__device__ __forceinline__ void glds16(const void* g, void* l) {
  __builtin_amdgcn_global_load_lds((const __attribute__((address_space(1))) unsigned int*)g,
                                   (__attribute__((address_space(3))) unsigned int*)l,
                                   16, 0, 0);
}

__device__ __forceinline__ f32x4 mfma16(short8 a, short8 b, f32x4 c) {
  return __builtin_amdgcn_mfma_f32_16x16x32_bf16(a, b, c, 0, 0, 0);
}

// ---------------- fused prep: weight transpose+cast (z<4) | x cast (z>=4) ----------------
// One launch replaces cast_x + transpose_cast_w (independent work, fills GPU better).
__global__ __launch_bounds__(256) void prep_kernel(
    const float* __restrict__ x, unsigned short* __restrict__ xb,
    const float* __restrict__ W0, const float* __restrict__ W1,
    const float* __restrict__ W2, const float* __restrict__ W3,
    unsigned short* __restrict__ Wt, unsigned short* __restrict__ Wot) {
  const int z = blockIdx.z;
  if (z >= 4) {  // cast x: 4096 virtual blocks, 8 elems/thread
    const long blk = (long)(z - 4) * 1024 + blockIdx.y * 32 + blockIdx.x;
    const long i = (blk * 256 + threadIdx.x) * 8;
    const float4 a = *(const float4*)(x + i);
    const float4 b = *(const float4*)(x + i + 4);
    unsigned short o[8] = {f2b(a.x), f2b(a.y), f2b(a.z), f2b(a.w),
                           f2b(b.x), f2b(b.y), f2b(b.z), f2b(b.w)};
    *(short8*)(xb + i) = *(const short8*)o;
    return;
  }
  // transpose+cast weights: dst[n][k] = W[k][n]
  const float* __restrict__ W = (z == 0) ? W0 : (z == 1) ? W1 : (z == 2) ? W2 : W3;
  unsigned short* __restrict__ dst = (z < 3) ? (Wt + (size_t)z * 1024 * 1024) : Wot;
  __shared__ float tile[32][33];
  const int tx = threadIdx.x & 31, ty = threadIdx.x >> 5;  // 32x8
  const int bx = blockIdx.x * 32, by = blockIdx.y * 32;
#pragma unroll
  for (int i = 0; i < 4; ++i)
    tile[ty + 8 * i][tx] = W[(size_t)(by + ty + 8 * i) * 1024 + bx + tx];
  __syncthreads();
#pragma unroll
  for (int i = 0; i < 4; ++i)
    dst[(size_t)(bx + ty + 8 * i) * 1024 + by + tx] = f2b(tile[tx][ty + 8 * i]);
}

// ---------------- QKV GEMM (M=8192,N=3072,K=1024) + fused RoPE/RMS epilogue ----------------
// r7-form: BK=64, row-XOR-swizzled LDS (conflict-free ds_read_b128), single-buffered.
// Q pre-scaled by (1/sqrt(D)) * log2(e) so attention scores are in log2 domain.
__global__ __launch_bounds__(256) void gemm_qkv(
    const unsigned short* __restrict__ A, const unsigned short* __restrict__ Bt,
    unsigned short* __restrict__ Qr, unsigned short* __restrict__ Kr,
    unsigned short* __restrict__ Vr,
    const float* __restrict__ cosp, const float* __restrict__ sinp) {
  __shared__ unsigned short As[128 * 64];
  __shared__ unsigned short Bs[128 * 64];
  const int tid = threadIdx.x;
  const int wave = tid >> 6, lane = tid & 63;
  const int ln = lane & 15, grp = lane >> 4;
  const int wr = wave >> 1, wc = wave & 1;
  const int row0 = blockIdx.x * 128, col0 = blockIdx.y * 128;

  f32x4 acc[4][4];
  const f32x4 z4 = {0.f, 0.f, 0.f, 0.f};
#pragma unroll
  for (int m = 0; m < 4; ++m)
#pragma unroll
    for (int n = 0; n < 4; ++n) acc[m][n] = z4;

  const int sw = (ln & 7) << 4;  // read-side XOR (row&7 == ln&7 for frag rows)

  for (int k0 = 0; k0 < 1024; k0 += 64) {
    __syncthreads();
#pragma unroll
    for (int it = 0; it < 4; ++it) {
      const int cl = it * 256 + tid;              // 16B chunk id 0..1023
      const int r = cl >> 3;                      // tile row 0..127
      const int sc = ((cl & 7) ^ (r & 7)) * 8;    // pre-swizzled source col (elems)
      glds16(A + (long)(row0 + r) * 1024 + k0 + sc, (char*)As + it * 4096 + wave * 1024);
      glds16(Bt + (long)(col0 + r) * 1024 + k0 + sc, (char*)Bs + it * 4096 + wave * 1024);
    }
    __syncthreads();
#pragma unroll
    for (int ks = 0; ks < 2; ++ks) {
      short8 af[4], bfv[4];
#pragma unroll
      for (int m = 0; m < 4; ++m) {
        const int row = wr * 64 + m * 16 + ln;
        af[m] = *(const short8*)((const char*)As + row * 128 + ((grp * 16 + ks * 64) ^ sw));
      }
#pragma unroll
      for (int n = 0; n < 4; ++n) {
        const int row = wc * 64 + n * 16 + ln;
        bfv[n] = *(const short8*)((const char*)Bs + row * 128 + ((grp * 16 + ks * 64) ^ sw));
      }
#pragma unroll
      for (int m = 0; m < 4; ++m)
#pragma unroll
        for (int n = 0; n < 4; ++n)
          acc[m][n] = mfma16(af[m], bfv[n], acc[m][n]);
    }
  }

  const int colbase = col0 + wc * 64;
  const int z = colbase >> 10;
  const int h = (colbase & 1023) >> 6;
  unsigned short* __restrict__ dst = (z == 0) ? Qr : (z == 1) ? Kr : Vr;

  if (z < 2) {  // RoPE + RMS-norm for Q,K (Q pre-scaled: 0.125 * log2(e))
    const float qs = (z == 0) ? 0.125f * 1.44269504f : 1.0f;
#pragma unroll
    for (int m = 0; m < 4; ++m) {
#pragma unroll
      for (int reg = 0; reg < 4; ++reg) {
        const int row = row0 + wr * 64 + m * 16 + grp * 4 + reg;
        const int t = row & 2047, b = row >> 11;
        const float u0 = acc[m][0][reg], u1 = acc[m][1][reg];
        const float u2 = acc[m][2][reg], u3 = acc[m][3][reg];
        const float c0 = cosp[t * 32 + ln],      s0 = sinp[t * 32 + ln];
        const float c1 = cosp[t * 32 + 16 + ln], s1 = sinp[t * 32 + 16 + ln];
        const float r0 =  u0 * c0 + u2 * s0;
        const float r1 =  u1 * c1 + u3 * s1;
        const float r2 = -u0 * s0 + u2 * c0;
        const float r3 = -u1 * s1 + u3 * c1;
        float ss = r0 * r0 + r1 * r1 + r2 * r2 + r3 * r3;
        ss += __shfl_xor(ss, 1); ss += __shfl_xor(ss, 2);
        ss += __shfl_xor(ss, 4); ss += __shfl_xor(ss, 8);
        const float inv = rsqrtf(ss * (1.0f / 64.0f) + 1.1920929e-07f) * qs;
        const long base = (((long)(b * 16 + h)) * 2048 + t) * 64;
        dst[base + ln]      = f2b(r0 * inv);
        dst[base + 16 + ln] = f2b(r1 * inv);
        dst[base + 32 + ln] = f2b(r2 * inv);
        dst[base + 48 + ln] = f2b(r3 * inv);
      }
    }
  } else {  // plain relayout for V
#pragma unroll
    for (int m = 0; m < 4; ++m) {
#pragma unroll
      for (int reg = 0; reg < 4; ++reg) {
        const int row = row0 + wr * 64 + m * 16 + grp * 4 + reg;
        const int t = row & 2047, b = row >> 11;
        const long base = (((long)(b * 16 + h)) * 2048 + t) * 64;
#pragma unroll
        for (int n = 0; n < 4; ++n)
          dst[base + n * 16 + ln] = f2b(acc[m][n][reg]);
      }
    }
  }
}

// ---------------- causal flash attention (r9: staged K+V, fixed-max, ones-MFMA l) -------
// Q/K/V: bf16 [B*H][T][64]; Y: bf16 [B][T][H][64]
// Fixed-max softmax (RMS-norm bounds |s_log2| <= 11.6): P = exp2(s) raw, no shift.
// l accumulated on the MATRIX pipe: extra MFMA with A = ones => D[r][q] = sum_kv P.
// 1024 blocks, 64-row q-tiles paired {bx, 31-bx} => uniform 33 kv-iters/block.
__global__ __launch_bounds__(256) void attn_kernel(
    const unsigned short* __restrict__ Q, const unsigned short* __restrict__ K,
    const unsigned short* __restrict__ V, unsigned short* __restrict__ Y) {
  // per buffer (u16): K [64][64] XOR-swizzled (8KB) | V subtiled [dt4][kvt16][4][16] (8KB)
  __shared__ unsigned short lds[2 * 8192];
  const int tid = threadIdx.x;
  const int wave = tid >> 6, lane = tid & 63;
  const int ln = lane & 15, grp = lane >> 4;

  const int linb = blockIdx.x;            // 1024 blocks
  const int xcd = linb & 7, slot = linb >> 3;
  const int bh = xcd * 8 + (slot >> 4);   // 8 heads per XCD => K/V L2-resident
  const int pr = slot & 15;               // 16 tile-pairs per bh

  const long bhT = (long)bh * 2048;
  const int b = bh >> 4, h = bh & 15;
  auto* lds3 = (__attribute__((address_space(3))) unsigned short*)lds;

  const short o1 = (short)0x3f80;  // bf16 1.0
  const short8 ones = {o1, o1, o1, o1, o1, o1, o1, o1};

  auto stage = [&](int j, int buf) {
    const long kvoff = bhT + (long)j * 64;
    char* Kb = (char*)lds + buf * 16384;
#pragma unroll
    for (int p = 0; p < 2; ++p) {
      const int cl = p * 256 + tid;                      // 16B chunk id 0..511
      const int krow = cl >> 3;
      const int kcb = ((cl & 7) * 16) ^ ((krow & 7) << 4);
      glds16(K + (kvoff + krow) * 64 + (kcb >> 1), Kb + p * 4096 + wave * 1024);
      const int dtv = cl >> 7, kvt = (cl >> 3) & 15, rr = (cl >> 1) & 3, hf = cl & 1;
      glds16(V + (kvoff + kvt * 4 + rr) * 64 + dtv * 16 + hf * 8,
             Kb + 8192 + p * 4096 + wave * 1024);
    }
  };

  const f32x4 z4 = {0.f, 0.f, 0.f, 0.f};

  for (int half = 0; half < 2; ++half) {
    const int bx = (half == 0) ? pr : 31 - pr;   // 64-row q-tile index
    const int qw = bx * 64 + wave * 16;          // this wave's 16 q-rows
    const int jmax = bx;                         // kv tiles 0..bx; only j==bx masked

    short8 qf[2];
#pragma unroll
    for (int c = 0; c < 2; ++c)
      qf[c] = *(const short8*)(Q + (bhT + qw + ln) * 64 + c * 32 + grp * 8);

    f32x4 accO[4];
#pragma unroll
    for (int dt = 0; dt < 4; ++dt) accO[dt] = z4;
    f32x4 accL = z4;   // l accumulator: lane's reg0 ends with l for q=ln

    stage(0, 0);
    asm volatile("s_waitcnt vmcnt(0)" ::: "memory");
    __builtin_amdgcn_s_barrier();

    int cur = 0;
    for (int j = 0; j <= jmax; ++j, cur ^= 1) {
      if (j < jmax) {
        stage(j + 1, cur ^ 1);
        asm volatile("s_waitcnt vmcnt(4)" ::: "memory");
      } else {
        asm volatile("s_waitcnt vmcnt(0)" ::: "memory");
      }
      __builtin_amdgcn_s_barrier();

      const unsigned short* Kb = lds + cur * 8192;
      const bool maskp = (j == jmax);

      // S^T = K * Q^T : lane holds S^T[kv=ct*16+grp*4+r][q=ln] (log2 domain)
      f32x4 sacc[4];
#pragma unroll
      for (int ct = 0; ct < 4; ++ct) sacc[ct] = z4;
      __builtin_amdgcn_s_setprio(1);
#pragma unroll
      for (int ct = 0; ct < 4; ++ct) {
        const int row = ct * 16 + ln;
        const int sw = (ln & 7) << 4;
        const char* rp = (const char*)Kb + row * 128;
        const short8 kf0 = *(const short8*)(rp + ((grp * 16) ^ sw));
        const short8 kf1 = *(const short8*)(rp + ((grp * 16 + 64) ^ sw));
        sacc[ct] = mfma16(kf0, qf[0], sacc[ct]);
        sacc[ct] = mfma16(kf1, qf[1], sacc[ct]);
      }
      __builtin_amdgcn_s_setprio(0);

      // fixed-max softmax: P = exp2(s) raw (s <= 11.6 => P <= ~3200, bf16-safe);
      // masked lanes -> exp2(-inf) = 0. No shift, no reduction (l via MFMA below).
      short8 pf[2];
      {
        if (maskp) {
          const int q = qw + ln;
#pragma unroll
          for (int ct = 0; ct < 4; ++ct)
#pragma unroll
            for (int r = 0; r < 4; ++r) {
              const int kv = j * 64 + ct * 16 + grp * 4 + r;
              if (kv > q) sacc[ct][r] = -INFINITY;
            }
        }
#pragma unroll
        for (int ct = 0; ct < 4; ++ct)
#pragma unroll
          for (int r = 0; r < 4; ++r)
            pf[ct >> 1][(ct & 1) * 4 + r] = (short)b16(exp2f(sacc[ct][r]));
      }

      // O^T += V^T * P^T ; V^T A-frags via hardware transpose-read.
      // "=&v" early-clobber REQUIRED (async writeback must not alias the address).
      const unsigned vb = (unsigned)(size_t)&lds3[cur * 8192 + 4096] + (unsigned)lane * 8;
      short4v t[4][4];
#pragma unroll
      for (int dt = 0; dt < 4; ++dt) {
        const unsigned va = vb + dt * 2048;
        asm volatile("ds_read_b64_tr_b16 %0, %4 offset:0\n\t"
                     "ds_read_b64_tr_b16 %1, %4 offset:512\n\t"
                     "ds_read_b64_tr_b16 %2, %4 offset:1024\n\t"
                     "ds_read_b64_tr_b16 %3, %4 offset:1536"
                     : "=&v"(t[dt][0]), "=&v"(t[dt][1]), "=&v"(t[dt][2]), "=&v"(t[dt][3])
                     : "v"(va));
      }
      asm volatile("s_waitcnt lgkmcnt(0)" ::: "memory");
      __builtin_amdgcn_sched_barrier(0);
      __builtin_amdgcn_s_setprio(1);
#pragma unroll
      for (int dt = 0; dt < 4; ++dt) {
        const short8 vf0 = __builtin_shufflevector(t[dt][0], t[dt][1], 0, 1, 2, 3, 4, 5, 6, 7);
        const short8 vf1 = __builtin_shufflevector(t[dt][2], t[dt][3], 0, 1, 2, 3, 4, 5, 6, 7);
        accO[dt] = mfma16(vf0, pf[0], accO[dt]);
        accO[dt] = mfma16(vf1, pf[1], accO[dt]);
      }
      accL = mfma16(ones, pf[0], accL);   // l_q = sum_kv P[kv][q]
      accL = mfma16(ones, pf[1], accL);
      __builtin_amdgcn_s_setprio(0);
      __builtin_amdgcn_s_barrier();
    }

    // epilogue: Y[b][t][h][d]; lane holds O^T[d=dt*16+grp*4+r][q=ln of tile];
    // accL[0] already holds this lane's q-column denominator (no cross-lane reduce).
    {
      const float inv = 1.0f / accL[0];
      const int t_ = qw + ln;
      const long base = (((long)(b * 2048 + t_)) * 16 + h) * 64;
#pragma unroll
      for (int dt = 0; dt < 4; ++dt) {
        unsigned short o[4];
#pragma unroll
        for (int r = 0; r < 4; ++r) o[r] = b16(accO[dt][r] * inv);
        *(short4v*)(Y + base + dt * 16 + grp * 4) = *(const short4v*)o;
      }
    }
  }
}

// ---------------- output GEMM (M=8192,N=1024,K=1024), f32 out ----------------
// r7-form: BK=64, row-XOR-swizzled LDS, single-buffered.
__global__ __launch_bounds__(256) void gemm_out(
    const unsigned short* __restrict__ A, const unsigned short* __restrict__ Bt,
    float* __restrict__ C) {
  __shared__ unsigned short As[128 * 64];
  __shared__ unsigned short Bs[128 * 64];
  const int tid = threadIdx.x;
  const int wave = tid >> 6, lane = tid & 63;
  const int ln = lane & 15, grp = lane >> 4;
  const int wr = wave >> 1, wc = wave & 1;
  const int row0 = blockIdx.x * 128, col0 = blockIdx.y * 128;

  f32x4 acc[4][4];
  const f32x4 z4 = {0.f, 0.f, 0.f, 0.f};
#pragma unroll
  for (int m = 0; m < 4; ++m)
#pragma unroll
    for (int n = 0; n < 4; ++n) acc[m][n] = z4;

  const int sw = (ln & 7) << 4;

  for (int k0 = 0; k0 < 1024; k0 += 64) {
    __syncthreads();
#pragma unroll
    for (int it = 0; it < 4; ++it) {
      const int cl = it * 256 + tid;
      const int r = cl >> 3;
      const int sc = ((cl & 7) ^ (r & 7)) * 8;
      glds16(A + (long)(row0 + r) * 1024 + k0 + sc, (char*)As + it * 4096 + wave * 1024);
      glds16(Bt + (long)(col0 + r) * 1024 + k0 + sc, (char*)Bs + it * 4096 + wave * 1024);
    }
    __syncthreads();
#pragma unroll
    for (int ks = 0; ks < 2; ++ks) {
      short8 af[4], bfv[4];
#pragma unroll
      for (int m = 0; m < 4; ++m) {
        const int row = wr * 64 + m * 16 + ln;
        af[m] = *(const short8*)((const char*)As + row * 128 + ((grp * 16 + ks * 64) ^ sw));
      }
#pragma unroll
      for (int n = 0; n < 4; ++n) {
        const int row = wc * 64 + n * 16 + ln;
        bfv[n] = *(const short8*)((const char*)Bs + row * 128 + ((grp * 16 + ks * 64) ^ sw));
      }
#pragma unroll
      for (int m = 0; m < 4; ++m)
#pragma unroll
        for (int n = 0; n < 4; ++n)
          acc[m][n] = mfma16(af[m], bfv[n], acc[m][n]);
    }
  }

#pragma unroll
  for (int m = 0; m < 4; ++m)
#pragma unroll
    for (int reg = 0; reg < 4; ++reg) {
      const int row = row0 + wr * 64 + m * 16 + grp * 4 + reg;
#pragma unroll
      for (int n = 0; n < 4; ++n)
        C[(long)row * 1024 + col0 + wc * 64 + n * 16 + ln] = acc[m][n][reg];
    }
}

extern "C" void kernel_launch(void* const* d_in, const int* in_sizes, int n_in,
                              void* d_out, int out_size, void* d_ws, size_t ws_size,
                              hipStream_t stream) {
  (void)in_sizes; (void)n_in; (void)out_size; (void)ws_size;
  const float* x    = (const float*)d_in[0];
  const float* cosp = (const float*)d_in[1];
  const float* sinp = (const float*)d_in[2];
  const float* Wq   = (const float*)d_in[3];
  const float* Wk   = (const float*)d_in[4];
  const float* Wv   = (const float*)d_in[5];
  const float* Wo   = (const float*)d_in[6];
  float* out = (float*)d_out;

  unsigned short* xb  = (unsigned short*)d_ws;
  unsigned short* Wt  = xb  + (size_t)8192 * 1024;
  unsigned short* Wot = Wt  + (size_t)3 * 1024 * 1024;
  unsigned short* Qr  = Wot + (size_t)1024 * 1024;
  unsigned short* Kr  = Qr  + (size_t)8192 * 1024;
  unsigned short* Vr  = Kr  + (size_t)8192 * 1024;
  unsigned short* Yb  = xb;  // xb dead after gemm_qkv

  prep_kernel<<<dim3(32, 32, 8), 256, 0, stream>>>(x, xb, Wq, Wk, Wv, Wo, Wt, Wot);
  gemm_qkv<<<dim3(64, 24), 256, 0, stream>>>(xb, Wt, Qr, Kr, Vr, cosp, sinp);
  attn_kernel<<<1024, 256, 0, stream>>>(Qr, Kr, Vr, Yb);
  gemm_out<<<dim3(64, 8), 256, 0, stream>>>(Yb, Wot, out);
}